// Round 10
// baseline (609.526 us; speedup 1.0000x reference)
//
#include <hip/hip_runtime.h>
#include <hip/hip_bf16.h>

#define N_NODES 50000
#define N_EDGES 1600000
#define NHALF   25000u     // source-half split for L2-resident gather passes
#define HDIM    128
#define NCLS    10
#define NGRAPH  64
#define NBKT    391        // buckets of 128 nodes: col>>7
#define HB      391        // histogram/scatter blocks: 4096 edges each

typedef __attribute__((ext_vector_type(8))) short bf16x8;
typedef __attribute__((ext_vector_type(4))) float f32x4;
typedef __attribute__((ext_vector_type(2))) float f32x2;
typedef __attribute__((ext_vector_type(2))) unsigned int u32x2;

// float -> bf16 bits (round-to-nearest-even), values are finite
__device__ inline unsigned int f2bf(float x) {
    unsigned int u = __float_as_uint(x);
    return (u + 0x7FFFu + ((u >> 16) & 1u)) >> 16;
}
__device__ inline float bf2f(unsigned int h) { return __uint_as_float(h << 16); }

__device__ inline f32x4 mfma16(bf16x8 a, bf16x8 b, f32x4 c) {
    return __builtin_amdgcn_mfma_f32_16x16x32_bf16(a, b, c, 0, 0, 0);
}

// ---------------- hist: per-block bucket histogram (col>>7) + sumsq ----------------
__global__ __launch_bounds__(256) void hist_kernel(const int* __restrict__ col,
                                                   const float* __restrict__ ew,
                                                   float* __restrict__ sumsq,
                                                   int* __restrict__ Hg) {
    __shared__ int hist[NBKT];
    __shared__ float part[4];
    int b = blockIdx.x, t = threadIdx.x;
    for (int i = t; i < NBKT; i += 256) hist[i] = 0;
    __syncthreads();
    int base = b * 4096;
    float ss = 0.f;
#pragma unroll
    for (int j = 0; j < 16; ++j) {
        int idx = base + j * 256 + t;
        if (idx < N_EDGES) {
            atomicAdd(&hist[col[idx] >> 7], 1);
            float w = ew[idx];
            ss += w * w;
        }
    }
#pragma unroll
    for (int off = 32; off > 0; off >>= 1) ss += __shfl_down(ss, off);
    if ((t & 63) == 0) part[t >> 6] = ss;
    __syncthreads();
    if (t == 0) unsafeAtomicAdd(sumsq, part[0] + part[1] + part[2] + part[3]);
    for (int i = t; i < NBKT; i += 256) Hg[i * HB + b] = hist[i];
}

// ---------------- btot: per-bucket total over blocks ----------------
__global__ __launch_bounds__(256) void btot_kernel(const int* __restrict__ Hg,
                                                   int* __restrict__ Bt) {
    __shared__ int s[256];
    int i = blockIdx.x, t = threadIdx.x;
    int v = (t < HB) ? Hg[i * HB + t] : 0;
    if (t + 256 < HB) v += Hg[i * HB + t + 256];
    s[t] = v;
    __syncthreads();
#pragma unroll
    for (int off = 128; off > 0; off >>= 1) {
        if (t < off) s[t] += s[t + off];
        __syncthreads();
    }
    if (t == 0) Bt[i] = s[0];
}

// ---------------- bscan: exclusive scan of bucket totals -> bucket bases ----------------
__global__ __launch_bounds__(512) void bscan_kernel(const int* __restrict__ Bt,
                                                    int* __restrict__ Bb) {
    __shared__ int s[512];
    int t = threadIdx.x;
    int v = (t < NBKT) ? Bt[t] : 0;
    s[t] = v;
    __syncthreads();
#pragma unroll
    for (int off = 1; off < 512; off <<= 1) {
        int add = (t >= off) ? s[t - off] : 0;
        __syncthreads();
        s[t] += add;
        __syncthreads();
    }
    if (t < NBKT) Bb[t] = s[t] - v;
    if (t == 0) Bb[NBKT] = N_EDGES;
}

// ---------------- hscan: per-bucket exclusive scan over blocks + bucket base ----------------
__global__ __launch_bounds__(512) void hscan_kernel(const int* __restrict__ Bb,
                                                    int* __restrict__ Hg) {
    __shared__ int s[512];
    int i = blockIdx.x, t = threadIdx.x;
    int v = (t < HB) ? Hg[i * HB + t] : 0;
    s[t] = v;
    __syncthreads();
#pragma unroll
    for (int off = 1; off < 512; off <<= 1) {
        int add = (t >= off) ? s[t - off] : 0;
        __syncthreads();
        s[t] += add;
        __syncthreads();
    }
    if (t < HB) Hg[i * HB + t] = Bb[i] + s[t] - v;
}

// ---------------- scat: bucket-grouped records (col16|row16, ew) via LDS cursors ----------------
__global__ __launch_bounds__(256) void scat_kernel(const int* __restrict__ col,
                                                   const int* __restrict__ row,
                                                   const float* __restrict__ ew,
                                                   const int* __restrict__ Hg,
                                                   uint2* __restrict__ R) {
    __shared__ int cur[NBKT];
    int b = blockIdx.x, t = threadIdx.x;
    for (int i = t; i < NBKT; i += 256) cur[i] = Hg[i * HB + b];
    __syncthreads();
    int base = b * 4096;
#pragma unroll
    for (int j = 0; j < 16; ++j) {
        int idx = base + j * 256 + t;
        if (idx < N_EDGES) {
            int c = col[idx];
            int r = row[idx];
            float w = ew[idx];
            int slot = atomicAdd(&cur[c >> 7], 1);
            R[slot] = make_uint2(((unsigned int)c << 16) | (unsigned int)r,
                                 __float_as_uint(w));
        }
    }
}

// ---- nstat: per-bucket node stats + rowptr/rowmid + dis + node-sort (A-half then B-half) ----
__global__ __launch_bounds__(256) void nstat_kernel(const uint2* __restrict__ R,
                                                    const int* __restrict__ Bb,
                                                    const float* __restrict__ sumsq,
                                                    float* __restrict__ dis,
                                                    int* __restrict__ rowptr,
                                                    int* __restrict__ rowmid,
                                                    uint2* __restrict__ S) {
    __shared__ int cnt[128];
    __shared__ int cntB[128];
    __shared__ float degf[128];
    __shared__ int scn[128];
    __shared__ int locA[128];
    __shared__ int locB[128];
    int bkt = blockIdx.x, t = threadIdx.x;
    int bstart = Bb[bkt], bend = Bb[bkt + 1];
    int node0 = bkt << 7;
    if (t < 128) { cnt[t] = 0; cntB[t] = 0; degf[t] = 0.f; }
    __syncthreads();
    for (int i = bstart + t; i < bend; i += 256) {
        uint2 r = R[i];
        int cl = (int)(r.x >> 16) - node0;
        atomicAdd(&cnt[cl], 1);
        if ((r.x & 0xFFFFu) >= NHALF) atomicAdd(&cntB[cl], 1);
        atomicAdd(&degf[cl], __uint_as_float(r.y));
    }
    __syncthreads();
    if (t < 128) scn[t] = cnt[t];
    __syncthreads();
#pragma unroll
    for (int off = 1; off < 128; off <<= 1) {
        int add = (t < 128 && t >= off) ? scn[t - off] : 0;
        __syncthreads();
        if (t < 128) scn[t] += add;
        __syncthreads();
    }
    if (t < 128) {
        int excl = scn[t] - cnt[t];
        locA[t] = excl;
        locB[t] = excl + cnt[t] - cntB[t];
    }
    int nNodes = min(128, N_NODES - node0);
    if (t < nNodes) {
        int excl = scn[t] - cnt[t];
        rowptr[node0 + t] = bstart + excl;
        rowmid[node0 + t] = bstart + excl + cnt[t] - cntB[t];
        float rn = 1.f / fmaxf(sqrtf(sumsq[0]), 1e-12f);
        dis[node0 + t] = rsqrtf(1.f + degf[t] * rn);
    }
    if (bkt == NBKT - 1 && t == 0) rowptr[N_NODES] = bend;
    __syncthreads();
    for (int i = bstart + t; i < bend; i += 256) {
        uint2 r = R[i];
        int cl = (int)(r.x >> 16) - node0;
        int* lc = ((r.x & 0xFFFFu) >= NHALF) ? locB : locA;
        int slot = atomicAdd(&lc[cl], 1);
        S[bstart + slot] = r;
    }
}

// ---------------- fill2: sequential eps from node-sorted records ----------------
__global__ __launch_bounds__(256) void fill2_kernel(const uint2* __restrict__ S,
                                                    const float* __restrict__ sumsq,
                                                    const float* __restrict__ dis,
                                                    unsigned int* __restrict__ eps) {
    int e = blockIdx.x * 256 + threadIdx.x;
    if (e >= N_EDGES) return;
    uint2 rec = S[e];
    int c = (int)(rec.x >> 16);
    int r = (int)(rec.x & 0xFFFFu);
    float w = __uint_as_float(rec.y);
    float rn = 1.f / fmaxf(sqrtf(sumsq[0]), 1e-12f);
    float nr = dis[r] * (w * rn) * dis[c];
    eps[e] = (f2bf(nr * 0.0625f) << 16) | (unsigned int)r;
}

// ---------------- W -> Wt (transposed, hi/lo bf16 split) + init (sumsq=0, g=0) ----------------
__global__ __launch_bounds__(256) void wconv_kernel(const float* __restrict__ W0,
                                                    const float* __restrict__ W1,
                                                    const float* __restrict__ W2,
                                                    const float* __restrict__ W3,
                                                    const float* __restrict__ W4,
                                                    unsigned short* __restrict__ wthi,
                                                    unsigned short* __restrict__ wtlo,
                                                    float* __restrict__ sumsq,
                                                    float* __restrict__ g) {
    int fid = (blockIdx.y * 8 + blockIdx.x) * 256 + threadIdx.x;   // 0..10239
    if (fid < NGRAPH * HDIM) g[fid] = 0.f;
    if (fid == NGRAPH * HDIM) sumsq[0] = 0.f;

    const float* Ws[5] = {W0, W1, W2, W3, W4};
    const float* W = Ws[blockIdx.y];
    unsigned short* hi = wthi + blockIdx.y * 128 * 128;
    unsigned short* lo = wtlo + blockIdx.y * 128 * 128;
    int t = blockIdx.x * 256 + threadIdx.x;   // 0..2047
    int n  = t & 127;
    int kb = t >> 7;                          // 0..15
    unsigned int hh[8], ll[8];
#pragma unroll
    for (int j = 0; j < 8; ++j) {
        float w = W[(kb * 8 + j) * 128 + n];   // W[k][n] -> Wt[n][k]
        unsigned int hb = f2bf(w);
        float r = w - bf2f(hb);
        hh[j] = hb; ll[j] = f2bf(r);
    }
    uint4 vh, vl;
    vh.x = hh[0] | (hh[1] << 16); vh.y = hh[2] | (hh[3] << 16);
    vh.z = hh[4] | (hh[5] << 16); vh.w = hh[6] | (hh[7] << 16);
    vl.x = ll[0] | (ll[1] << 16); vl.y = ll[2] | (ll[3] << 16);
    vl.z = ll[4] | (ll[5] << 16); vl.w = ll[6] | (ll[7] << 16);
    *(uint4*)&hi[n * 128 + kb * 8] = vh;
    *(uint4*)&lo[n * 128 + kb * 8] = vl;
}

// ---------------- MFMA GEMM: M = A @ W, hpre = bias + dis^2*M (NT), mb8 = fp8(16*M) ----------------
template <int FP32A>
__global__ __launch_bounds__(256) void gemm_mfma(const float* __restrict__ Af,
                                                 const unsigned short* __restrict__ Ahi,
                                                 const unsigned short* __restrict__ Alo,
                                                 const unsigned short* __restrict__ Wthi,
                                                 const unsigned short* __restrict__ Wtlo,
                                                 const float* __restrict__ dis,
                                                 const float* __restrict__ bias,
                                                 float* __restrict__ hpre,
                                                 unsigned int* __restrict__ mb8,
                                                 int nrows) {
    const int lane = threadIdx.x & 63;
    const int wave = threadIdx.x >> 6;
    const int l15  = lane & 15;
    const int lq   = lane >> 4;              // 0..3
    const int mbase = blockIdx.x * 128 + wave * 32;

    f32x4 acc[2][8];
#pragma unroll
    for (int i = 0; i < 2; ++i)
#pragma unroll
        for (int j = 0; j < 8; ++j) acc[i][j] = (f32x4){0.f, 0.f, 0.f, 0.f};

#pragma unroll
    for (int ks = 0; ks < 4; ++ks) {
        const int kof = ks * 32 + lq * 8;
        bf16x8 wh[8], wl[8];
#pragma unroll
        for (int nt = 0; nt < 8; ++nt) {
            int n = nt * 16 + l15;
            wh[nt] = *(const bf16x8*)&Wthi[n * 128 + kof];
            wl[nt] = *(const bf16x8*)&Wtlo[n * 128 + kof];
        }
        bf16x8 ah[2], al[2];
#pragma unroll
        for (int mt = 0; mt < 2; ++mt) {
            int m = mbase + mt * 16 + l15;
            if (m < nrows) {
                if (FP32A) {
                    const float* ap = &Af[m * 128 + kof];
                    f32x4 v0 = __builtin_nontemporal_load((const f32x4*)&ap[0]);
                    f32x4 v1 = __builtin_nontemporal_load((const f32x4*)&ap[4]);
                    float xs[8] = {v0[0], v0[1], v0[2], v0[3], v1[0], v1[1], v1[2], v1[3]};
                    short hh[8], ll[8];
#pragma unroll
                    for (int j = 0; j < 8; ++j) {
                        unsigned int hb = f2bf(xs[j]);
                        float r = xs[j] - bf2f(hb);
                        hh[j] = (short)hb;
                        ll[j] = (short)f2bf(r);
                    }
                    ah[mt] = (bf16x8){hh[0], hh[1], hh[2], hh[3], hh[4], hh[5], hh[6], hh[7]};
                    al[mt] = (bf16x8){ll[0], ll[1], ll[2], ll[3], ll[4], ll[5], ll[6], ll[7]};
                } else {
                    ah[mt] = __builtin_nontemporal_load((const bf16x8*)&Ahi[m * 128 + kof]);
                    al[mt] = __builtin_nontemporal_load((const bf16x8*)&Alo[m * 128 + kof]);
                }
            } else {
                ah[mt] = (bf16x8){0, 0, 0, 0, 0, 0, 0, 0};
                al[mt] = (bf16x8){0, 0, 0, 0, 0, 0, 0, 0};
            }
        }
#pragma unroll
        for (int mt = 0; mt < 2; ++mt)
#pragma unroll
            for (int nt = 0; nt < 8; ++nt) {
                acc[mt][nt] = mfma16(wh[nt], ah[mt], acc[mt][nt]);
                acc[mt][nt] = mfma16(wl[nt], ah[mt], acc[mt][nt]);
                acc[mt][nt] = mfma16(wh[nt], al[mt], acc[mt][nt]);
            }
    }

    // epilogue: lane -> m = mbase+mt*16+l15 ; n0 = nt*16+lq*4
#pragma unroll
    for (int mt = 0; mt < 2; ++mt) {
        int m = mbase + mt * 16 + l15;
        if (m >= nrows) continue;
        float d = dis[m];
        float sn = d * d;
#pragma unroll
        for (int nt = 0; nt < 8; ++nt) {
            int n0 = nt * 16 + lq * 4;
            float4 bv = *(const float4*)&bias[n0];
            f32x4 a = acc[mt][nt];
            f32x4 hp = {bv.x + sn * a[0], bv.y + sn * a[1],
                        bv.z + sn * a[2], bv.w + sn * a[3]};
            __builtin_nontemporal_store(hp, (f32x4*)&hpre[m * 128 + n0]);
            int pk = __builtin_amdgcn_cvt_pk_fp8_f32(a[0] * 16.f, a[1] * 16.f, 0, false);
            pk = __builtin_amdgcn_cvt_pk_fp8_f32(a[2] * 16.f, a[3] * 16.f, pk, true);
            mb8[(m * 128 + n0) >> 2] = (unsigned int)pk;   // cacheable: random-read next
        }
    }
}

// ---- gather pass: PASS0 = low-half sources (hpre -> pbuf), PASS1 = high-half (pbuf -> hhi/hlo) ----
// 32 lanes x 128B full-line rows per node; mb8 reads cacheable (3.2MB working set/pass, L2-fit),
// all streaming traffic nontemporal so it doesn't evict mb8.
__device__ inline void accp(float4& a, float n, unsigned int m) {
    f32x2 lo = __builtin_amdgcn_cvt_pk_f32_fp8(m, false);
    f32x2 hi = __builtin_amdgcn_cvt_pk_f32_fp8(m, true);
    a.x = fmaf(n, lo[0], a.x);
    a.y = fmaf(n, lo[1], a.y);
    a.z = fmaf(n, hi[0], a.z);
    a.w = fmaf(n, hi[1], a.w);
}

template <int PASS>
__global__ __launch_bounds__(256) void gather_kernel(const int* __restrict__ rowptr,
                                                     const int* __restrict__ rowmid,
                                                     const unsigned int* __restrict__ eps,
                                                     const float* __restrict__ hpre,
                                                     float* __restrict__ pbuf,
                                                     const unsigned int* __restrict__ mb8,
                                                     unsigned short* __restrict__ hhi,
                                                     unsigned short* __restrict__ hlo) {
    int nid = blockIdx.x * 8 + (threadIdx.x >> 5);
    if (nid >= N_NODES) return;
    int fq = threadIdx.x & 31;
    int f = fq * 4;

    f32x4 av;
    int e, e1;
    if (PASS == 0) {
        av = __builtin_nontemporal_load((const f32x4*)&hpre[nid * HDIM + f]);
        e = rowptr[nid]; e1 = rowmid[nid];
    } else {
        av = __builtin_nontemporal_load((const f32x4*)&pbuf[nid * HDIM + f]);
        e = rowmid[nid]; e1 = rowptr[nid + 1];
    }
    float4 a = {av[0], av[1], av[2], av[3]};

    for (; e + 3 < e1; e += 4) {
        unsigned int p0 = __builtin_nontemporal_load(&eps[e]);
        unsigned int p1 = __builtin_nontemporal_load(&eps[e + 1]);
        unsigned int p2 = __builtin_nontemporal_load(&eps[e + 2]);
        unsigned int p3 = __builtin_nontemporal_load(&eps[e + 3]);
        unsigned int m0 = mb8[(p0 & 0xFFFFu) * 32 + fq];
        unsigned int m1 = mb8[(p1 & 0xFFFFu) * 32 + fq];
        unsigned int m2 = mb8[(p2 & 0xFFFFu) * 32 + fq];
        unsigned int m3 = mb8[(p3 & 0xFFFFu) * 32 + fq];
        accp(a, __uint_as_float(p0 & 0xFFFF0000u), m0);
        accp(a, __uint_as_float(p1 & 0xFFFF0000u), m1);
        accp(a, __uint_as_float(p2 & 0xFFFF0000u), m2);
        accp(a, __uint_as_float(p3 & 0xFFFF0000u), m3);
    }
    for (; e < e1; ++e) {
        unsigned int p0 = __builtin_nontemporal_load(&eps[e]);
        unsigned int m0 = mb8[(p0 & 0xFFFFu) * 32 + fq];
        accp(a, __uint_as_float(p0 & 0xFFFF0000u), m0);
    }

    if (PASS == 0) {
        f32x4 o = {a.x, a.y, a.z, a.w};
        __builtin_nontemporal_store(o, (f32x4*)&pbuf[nid * HDIM + f]);
    } else {
        float xs[4] = {fmaxf(a.x, 0.f), fmaxf(a.y, 0.f), fmaxf(a.z, 0.f), fmaxf(a.w, 0.f)};
        unsigned int hb[4], lb[4];
#pragma unroll
        for (int j = 0; j < 4; ++j) {
            hb[j] = f2bf(xs[j]);
            lb[j] = f2bf(xs[j] - bf2f(hb[j]));
        }
        u32x2 vh = {hb[0] | (hb[1] << 16), hb[2] | (hb[3] << 16)};
        u32x2 vl = {lb[0] | (lb[1] << 16), lb[2] | (lb[3] << 16)};
        __builtin_nontemporal_store(vh, (u32x2*)&hhi[nid * HDIM + f]);
        __builtin_nontemporal_store(vl, (u32x2*)&hlo[nid * HDIM + f]);
    }
}

// ---------------- pool: g[batch[i]] += h[i] (h already relu'd); batch sorted ----------------
__global__ __launch_bounds__(256) void pool_kernel(const unsigned short* __restrict__ hhi,
                                                   const unsigned short* __restrict__ hlo,
                                                   const int* __restrict__ batch,
                                                   float* __restrict__ g) {
    int f = threadIdx.x & 127;
    int ty = threadIdx.x >> 7;
    int i0 = blockIdx.x * 128 + ty;
    int iend = min(blockIdx.x * 128 + 128, N_NODES);
    float acc = 0.f;
    int cur = -1;
    for (int i = i0; i < iend; i += 2) {
        int bb = batch[i];
        if (bb != cur) {
            if (cur >= 0) unsafeAtomicAdd(&g[cur * HDIM + f], acc);
            acc = 0.f;
            cur = bb;
        }
        acc += bf2f(hhi[i * HDIM + f]) + bf2f(hlo[i * HDIM + f]);
    }
    if (cur >= 0) unsafeAtomicAdd(&g[cur * HDIM + f], acc);
}

// ---------------- MLP head + log_softmax: one block per graph ----------------
__global__ __launch_bounds__(128) void mlp_kernel(const float* __restrict__ g,
                                                  const float* __restrict__ lw1,
                                                  const float* __restrict__ lb1,
                                                  const float* __restrict__ lw2,
                                                  const float* __restrict__ lb2,
                                                  float* __restrict__ out) {
    __shared__ float sg[128];
    __shared__ float sh[128];
    __shared__ float sl[NCLS];
    __shared__ float s_lse;
    int b = blockIdx.x;
    int t = threadIdx.x;
    sg[t] = g[b * HDIM + t];
    __syncthreads();
    float acc = lb1[t];
    for (int k = 0; k < 128; ++k) acc = fmaf(sg[k], lw1[k * 128 + t], acc);
    sh[t] = fmaxf(acc, 0.f);
    __syncthreads();
    if (t < NCLS) {
        float a2 = lb2[t];
        for (int j = 0; j < 128; ++j) a2 = fmaf(sh[j], lw2[j * NCLS + t], a2);
        sl[t] = a2;
    }
    __syncthreads();
    if (t == 0) {
        float mx = sl[0];
        for (int c = 1; c < NCLS; ++c) mx = fmaxf(mx, sl[c]);
        float se = 0.f;
        for (int c = 0; c < NCLS; ++c) se += expf(sl[c] - mx);
        s_lse = mx + logf(se);
    }
    __syncthreads();
    if (t < NCLS) out[b * NCLS + t] = sl[t] - s_lse;
}

extern "C" void kernel_launch(void* const* d_in, const int* in_sizes, int n_in,
                              void* d_out, int out_size, void* d_ws, size_t ws_size,
                              hipStream_t stream) {
    const float* x     = (const float*)d_in[0];
    const int*   ei    = (const int*)d_in[1];     // [2, E] flat
    const float* ew    = (const float*)d_in[2];
    const int*   batch = (const int*)d_in[3];
    const float* W[5]  = {(const float*)d_in[4],  (const float*)d_in[6],
                          (const float*)d_in[8],  (const float*)d_in[10],
                          (const float*)d_in[12]};
    const float* B[5]  = {(const float*)d_in[5],  (const float*)d_in[7],
                          (const float*)d_in[9],  (const float*)d_in[11],
                          (const float*)d_in[13]};
    const float* lw1   = (const float*)d_in[14];
    const float* lb1   = (const float*)d_in[15];
    const float* lw2   = (const float*)d_in[16];
    const float* lb2   = (const float*)d_in[17];
    float* out = (float*)d_out;

    const int* row = ei;
    const int* col = ei + N_EDGES;

    // workspace layout (4-byte words), ~112 MB total
    float* ws     = (float*)d_ws;
    float* sumsq  = ws;                                        // 16
    float* dis    = ws + 16;                                   // 50048
    int*   rowptr = (int*)(dis + 50048);                       // 50064
    int*   rowmid = rowptr + 50064;                            // 50048
    int*   Hg     = rowmid + 50048;                            // 152896 (391*391 padded)
    int*   Bt     = Hg + 152896;                               // 400
    int*   Bb     = Bt + 400;                                  // 400 (needs 392)
    uint2* R      = (uint2*)(Bb + 400);                        // E uint2 (3.2M words)
    uint2* S      = R + N_EDGES;                               // E uint2 (3.2M words)
    float* g      = (float*)(S + N_EDGES);                     // 8192
    unsigned short* wthi = (unsigned short*)(g + NGRAPH * HDIM); // 5*16384 us
    unsigned short* wtlo = wthi + 5 * 128 * 128;                 // 5*16384 us
    float* hpre   = (float*)(wtlo + 5 * 128 * 128);            // N*128 f32
    float* pbuf   = hpre + N_NODES * HDIM;                     // N*128 f32
    unsigned int* mb8 = (unsigned int*)(pbuf + N_NODES * HDIM); // N*32 u32 (fp8 m)
    unsigned short* hhi = (unsigned short*)(mb8 + N_NODES * 32); // N*128 us
    unsigned short* hlo = hhi + N_NODES * HDIM;                // N*128 us
    unsigned int* eps = (unsigned int*)R;                      // alias: R dead after nstat

    const int EB = N_EDGES / 256;                              // 6250

    wconv_kernel<<<dim3(8, 5), 256, 0, stream>>>(W[0], W[1], W[2], W[3], W[4],
                                                 wthi, wtlo, sumsq, g);
    hist_kernel<<<HB, 256, 0, stream>>>(col, ew, sumsq, Hg);
    btot_kernel<<<NBKT, 256, 0, stream>>>(Hg, Bt);
    bscan_kernel<<<1, 512, 0, stream>>>(Bt, Bb);
    hscan_kernel<<<NBKT, 512, 0, stream>>>(Bb, Hg);
    scat_kernel<<<HB, 256, 0, stream>>>(col, row, ew, Hg, R);
    nstat_kernel<<<NBKT, 256, 0, stream>>>(R, Bb, sumsq, dis, rowptr, rowmid, S);
    fill2_kernel<<<EB, 256, 0, stream>>>(S, sumsq, dis, eps);

    const int GEMM_B = (N_NODES + 127) / 128;                  // 391
    const int GATH_B = (N_NODES + 7) / 8;                      // 6250

    // layer 1: A = x (fp32, split in-kernel)
    gemm_mfma<1><<<GEMM_B, 256, 0, stream>>>(x, hhi, hlo, wthi, wtlo,
                                             dis, B[0], hpre, mb8, N_NODES);
    gather_kernel<0><<<GATH_B, 256, 0, stream>>>(rowptr, rowmid, eps, hpre, pbuf, mb8, hhi, hlo);
    gather_kernel<1><<<GATH_B, 256, 0, stream>>>(rowptr, rowmid, eps, hpre, pbuf, mb8, hhi, hlo);
    // layers 2..5: A = h (hi/lo bf16 split, pre-relu'd by gather)
    for (int l = 1; l < 5; ++l) {
        gemm_mfma<0><<<GEMM_B, 256, 0, stream>>>(x, hhi, hlo,
                                                 wthi + l * 128 * 128, wtlo + l * 128 * 128,
                                                 dis, B[l], hpre, mb8, N_NODES);
        gather_kernel<0><<<GATH_B, 256, 0, stream>>>(rowptr, rowmid, eps, hpre, pbuf, mb8, hhi, hlo);
        gather_kernel<1><<<GATH_B, 256, 0, stream>>>(rowptr, rowmid, eps, hpre, pbuf, mb8, hhi, hlo);
    }

    // pool + head
    pool_kernel<<<GEMM_B, 256, 0, stream>>>(hhi, hlo, batch, g);
    mlp_kernel<<<NGRAPH, 128, 0, stream>>>(g, lw1, lb1, lw2, lb2, out);
}

// Round 11
// 427.011 us; speedup vs baseline: 1.4274x; 1.4274x over previous
//
#include <hip/hip_runtime.h>
#include <hip/hip_bf16.h>

#define N_NODES 50000
#define N_EDGES 1600000
#define NHALF   25000u     // source-half ordering inside each node's edge list
#define HDIM    128
#define NCLS    10
#define NGRAPH  64
#define NBKT    391        // buckets of 128 nodes: col>>7
#define HB      391        // histogram/scatter blocks: 4096 edges each

typedef __attribute__((ext_vector_type(8))) short bf16x8;
typedef __attribute__((ext_vector_type(4))) float f32x4;
typedef __attribute__((ext_vector_type(2))) float f32x2;

// float -> bf16 bits (round-to-nearest-even), values are finite
__device__ inline unsigned int f2bf(float x) {
    unsigned int u = __float_as_uint(x);
    return (u + 0x7FFFu + ((u >> 16) & 1u)) >> 16;
}
__device__ inline float bf2f(unsigned int h) { return __uint_as_float(h << 16); }

__device__ inline f32x4 mfma16(bf16x8 a, bf16x8 b, f32x4 c) {
    return __builtin_amdgcn_mfma_f32_16x16x32_bf16(a, b, c, 0, 0, 0);
}

// ---------------- hist: per-block bucket histogram (col>>7) + sumsq ----------------
__global__ __launch_bounds__(256) void hist_kernel(const int* __restrict__ col,
                                                   const float* __restrict__ ew,
                                                   float* __restrict__ sumsq,
                                                   int* __restrict__ Hg) {
    __shared__ int hist[NBKT];
    __shared__ float part[4];
    int b = blockIdx.x, t = threadIdx.x;
    for (int i = t; i < NBKT; i += 256) hist[i] = 0;
    __syncthreads();
    int base = b * 4096;
    float ss = 0.f;
#pragma unroll
    for (int j = 0; j < 16; ++j) {
        int idx = base + j * 256 + t;
        if (idx < N_EDGES) {
            atomicAdd(&hist[col[idx] >> 7], 1);
            float w = ew[idx];
            ss += w * w;
        }
    }
#pragma unroll
    for (int off = 32; off > 0; off >>= 1) ss += __shfl_down(ss, off);
    if ((t & 63) == 0) part[t >> 6] = ss;
    __syncthreads();
    if (t == 0) unsafeAtomicAdd(sumsq, part[0] + part[1] + part[2] + part[3]);
    for (int i = t; i < NBKT; i += 256) Hg[i * HB + b] = hist[i];
}

// ---------------- btot: per-bucket total over blocks ----------------
__global__ __launch_bounds__(256) void btot_kernel(const int* __restrict__ Hg,
                                                   int* __restrict__ Bt) {
    __shared__ int s[256];
    int i = blockIdx.x, t = threadIdx.x;
    int v = (t < HB) ? Hg[i * HB + t] : 0;
    if (t + 256 < HB) v += Hg[i * HB + t + 256];
    s[t] = v;
    __syncthreads();
#pragma unroll
    for (int off = 128; off > 0; off >>= 1) {
        if (t < off) s[t] += s[t + off];
        __syncthreads();
    }
    if (t == 0) Bt[i] = s[0];
}

// ---------------- bscan: exclusive scan of bucket totals -> bucket bases ----------------
__global__ __launch_bounds__(512) void bscan_kernel(const int* __restrict__ Bt,
                                                    int* __restrict__ Bb) {
    __shared__ int s[512];
    int t = threadIdx.x;
    int v = (t < NBKT) ? Bt[t] : 0;
    s[t] = v;
    __syncthreads();
#pragma unroll
    for (int off = 1; off < 512; off <<= 1) {
        int add = (t >= off) ? s[t - off] : 0;
        __syncthreads();
        s[t] += add;
        __syncthreads();
    }
    if (t < NBKT) Bb[t] = s[t] - v;
    if (t == 0) Bb[NBKT] = N_EDGES;
}

// ---------------- hscan: per-bucket exclusive scan over blocks + bucket base ----------------
__global__ __launch_bounds__(512) void hscan_kernel(const int* __restrict__ Bb,
                                                    int* __restrict__ Hg) {
    __shared__ int s[512];
    int i = blockIdx.x, t = threadIdx.x;
    int v = (t < HB) ? Hg[i * HB + t] : 0;
    s[t] = v;
    __syncthreads();
#pragma unroll
    for (int off = 1; off < 512; off <<= 1) {
        int add = (t >= off) ? s[t - off] : 0;
        __syncthreads();
        s[t] += add;
        __syncthreads();
    }
    if (t < HB) Hg[i * HB + t] = Bb[i] + s[t] - v;
}

// ---------------- scat: bucket-grouped records (col16|row16, ew) via LDS cursors ----------------
__global__ __launch_bounds__(256) void scat_kernel(const int* __restrict__ col,
                                                   const int* __restrict__ row,
                                                   const float* __restrict__ ew,
                                                   const int* __restrict__ Hg,
                                                   uint2* __restrict__ R) {
    __shared__ int cur[NBKT];
    int b = blockIdx.x, t = threadIdx.x;
    for (int i = t; i < NBKT; i += 256) cur[i] = Hg[i * HB + b];
    __syncthreads();
    int base = b * 4096;
#pragma unroll
    for (int j = 0; j < 16; ++j) {
        int idx = base + j * 256 + t;
        if (idx < N_EDGES) {
            int c = col[idx];
            int r = row[idx];
            float w = ew[idx];
            int slot = atomicAdd(&cur[c >> 7], 1);
            R[slot] = make_uint2(((unsigned int)c << 16) | (unsigned int)r,
                                 __float_as_uint(w));
        }
    }
}

// ---- nstat: per-bucket node stats + rowptr + dis + node-sort (low-src segment first) ----
__global__ __launch_bounds__(256) void nstat_kernel(const uint2* __restrict__ R,
                                                    const int* __restrict__ Bb,
                                                    const float* __restrict__ sumsq,
                                                    float* __restrict__ dis,
                                                    int* __restrict__ rowptr,
                                                    uint2* __restrict__ S) {
    __shared__ int cnt[128];
    __shared__ int cntB[128];
    __shared__ float degf[128];
    __shared__ int scn[128];
    __shared__ int locA[128];
    __shared__ int locB[128];
    int bkt = blockIdx.x, t = threadIdx.x;
    int bstart = Bb[bkt], bend = Bb[bkt + 1];
    int node0 = bkt << 7;
    if (t < 128) { cnt[t] = 0; cntB[t] = 0; degf[t] = 0.f; }
    __syncthreads();
    for (int i = bstart + t; i < bend; i += 256) {
        uint2 r = R[i];
        int cl = (int)(r.x >> 16) - node0;
        atomicAdd(&cnt[cl], 1);
        if ((r.x & 0xFFFFu) >= NHALF) atomicAdd(&cntB[cl], 1);
        atomicAdd(&degf[cl], __uint_as_float(r.y));
    }
    __syncthreads();
    if (t < 128) scn[t] = cnt[t];
    __syncthreads();
#pragma unroll
    for (int off = 1; off < 128; off <<= 1) {
        int add = (t < 128 && t >= off) ? scn[t - off] : 0;
        __syncthreads();
        if (t < 128) scn[t] += add;
        __syncthreads();
    }
    if (t < 128) {
        int excl = scn[t] - cnt[t];
        locA[t] = excl;
        locB[t] = excl + cnt[t] - cntB[t];
    }
    int nNodes = min(128, N_NODES - node0);
    if (t < nNodes) {
        rowptr[node0 + t] = bstart + scn[t] - cnt[t];
        float rn = 1.f / fmaxf(sqrtf(sumsq[0]), 1e-12f);
        dis[node0 + t] = rsqrtf(1.f + degf[t] * rn);
    }
    if (bkt == NBKT - 1 && t == 0) rowptr[N_NODES] = bend;
    __syncthreads();
    for (int i = bstart + t; i < bend; i += 256) {
        uint2 r = R[i];
        int cl = (int)(r.x >> 16) - node0;
        int* lc = ((r.x & 0xFFFFu) >= NHALF) ? locB : locA;
        int slot = atomicAdd(&lc[cl], 1);
        S[bstart + slot] = r;
    }
}

// ---------------- fill2: sequential eps from node-sorted records ----------------
__global__ __launch_bounds__(256) void fill2_kernel(const uint2* __restrict__ S,
                                                    const float* __restrict__ sumsq,
                                                    const float* __restrict__ dis,
                                                    unsigned int* __restrict__ eps) {
    int e = blockIdx.x * 256 + threadIdx.x;
    if (e >= N_EDGES) return;
    uint2 rec = S[e];
    int c = (int)(rec.x >> 16);
    int r = (int)(rec.x & 0xFFFFu);
    float w = __uint_as_float(rec.y);
    float rn = 1.f / fmaxf(sqrtf(sumsq[0]), 1e-12f);
    float nr = dis[r] * (w * rn) * dis[c];
    eps[e] = (f2bf(nr * 0.0625f) << 16) | (unsigned int)r;
}

// ---------------- W -> Wt (transposed, hi/lo bf16 split) + init (sumsq=0, g=0) ----------------
__global__ __launch_bounds__(256) void wconv_kernel(const float* __restrict__ W0,
                                                    const float* __restrict__ W1,
                                                    const float* __restrict__ W2,
                                                    const float* __restrict__ W3,
                                                    const float* __restrict__ W4,
                                                    unsigned short* __restrict__ wthi,
                                                    unsigned short* __restrict__ wtlo,
                                                    float* __restrict__ sumsq,
                                                    float* __restrict__ g) {
    int fid = (blockIdx.y * 8 + blockIdx.x) * 256 + threadIdx.x;   // 0..10239
    if (fid < NGRAPH * HDIM) g[fid] = 0.f;
    if (fid == NGRAPH * HDIM) sumsq[0] = 0.f;

    const float* Ws[5] = {W0, W1, W2, W3, W4};
    const float* W = Ws[blockIdx.y];
    unsigned short* hi = wthi + blockIdx.y * 128 * 128;
    unsigned short* lo = wtlo + blockIdx.y * 128 * 128;
    int t = blockIdx.x * 256 + threadIdx.x;   // 0..2047
    int n  = t & 127;
    int kb = t >> 7;                          // 0..15
    unsigned int hh[8], ll[8];
#pragma unroll
    for (int j = 0; j < 8; ++j) {
        float w = W[(kb * 8 + j) * 128 + n];   // W[k][n] -> Wt[n][k]
        unsigned int hb = f2bf(w);
        float r = w - bf2f(hb);
        hh[j] = hb; ll[j] = f2bf(r);
    }
    uint4 vh, vl;
    vh.x = hh[0] | (hh[1] << 16); vh.y = hh[2] | (hh[3] << 16);
    vh.z = hh[4] | (hh[5] << 16); vh.w = hh[6] | (hh[7] << 16);
    vl.x = ll[0] | (ll[1] << 16); vl.y = ll[2] | (ll[3] << 16);
    vl.z = ll[4] | (ll[5] << 16); vl.w = ll[6] | (ll[7] << 16);
    *(uint4*)&hi[n * 128 + kb * 8] = vh;
    *(uint4*)&lo[n * 128 + kb * 8] = vl;
}

// ---------------- MFMA GEMM: M = A @ W, hpre = bias + dis^2*M, mb8 = fp8(16*M) ----------------
template <int FP32A>
__global__ __launch_bounds__(256) void gemm_mfma(const float* __restrict__ Af,
                                                 const unsigned short* __restrict__ Ahi,
                                                 const unsigned short* __restrict__ Alo,
                                                 const unsigned short* __restrict__ Wthi,
                                                 const unsigned short* __restrict__ Wtlo,
                                                 const float* __restrict__ dis,
                                                 const float* __restrict__ bias,
                                                 float* __restrict__ hpre,
                                                 unsigned int* __restrict__ mb8,
                                                 int nrows) {
    const int lane = threadIdx.x & 63;
    const int wave = threadIdx.x >> 6;
    const int l15  = lane & 15;
    const int lq   = lane >> 4;              // 0..3
    const int mbase = blockIdx.x * 128 + wave * 32;

    f32x4 acc[2][8];
#pragma unroll
    for (int i = 0; i < 2; ++i)
#pragma unroll
        for (int j = 0; j < 8; ++j) acc[i][j] = (f32x4){0.f, 0.f, 0.f, 0.f};

#pragma unroll
    for (int ks = 0; ks < 4; ++ks) {
        const int kof = ks * 32 + lq * 8;
        bf16x8 wh[8], wl[8];
#pragma unroll
        for (int nt = 0; nt < 8; ++nt) {
            int n = nt * 16 + l15;
            wh[nt] = *(const bf16x8*)&Wthi[n * 128 + kof];
            wl[nt] = *(const bf16x8*)&Wtlo[n * 128 + kof];
        }
        bf16x8 ah[2], al[2];
#pragma unroll
        for (int mt = 0; mt < 2; ++mt) {
            int m = mbase + mt * 16 + l15;
            if (m < nrows) {
                if (FP32A) {
                    const float* ap = &Af[m * 128 + kof];
                    float4 v0 = *(const float4*)&ap[0];
                    float4 v1 = *(const float4*)&ap[4];
                    float xs[8] = {v0.x, v0.y, v0.z, v0.w, v1.x, v1.y, v1.z, v1.w};
                    short hh[8], ll[8];
#pragma unroll
                    for (int j = 0; j < 8; ++j) {
                        unsigned int hb = f2bf(xs[j]);
                        float r = xs[j] - bf2f(hb);
                        hh[j] = (short)hb;
                        ll[j] = (short)f2bf(r);
                    }
                    ah[mt] = (bf16x8){hh[0], hh[1], hh[2], hh[3], hh[4], hh[5], hh[6], hh[7]};
                    al[mt] = (bf16x8){ll[0], ll[1], ll[2], ll[3], ll[4], ll[5], ll[6], ll[7]};
                } else {
                    ah[mt] = *(const bf16x8*)&Ahi[m * 128 + kof];
                    al[mt] = *(const bf16x8*)&Alo[m * 128 + kof];
                }
            } else {
                ah[mt] = (bf16x8){0, 0, 0, 0, 0, 0, 0, 0};
                al[mt] = (bf16x8){0, 0, 0, 0, 0, 0, 0, 0};
            }
        }
#pragma unroll
        for (int mt = 0; mt < 2; ++mt)
#pragma unroll
            for (int nt = 0; nt < 8; ++nt) {
                acc[mt][nt] = mfma16(wh[nt], ah[mt], acc[mt][nt]);
                acc[mt][nt] = mfma16(wl[nt], ah[mt], acc[mt][nt]);
                acc[mt][nt] = mfma16(wh[nt], al[mt], acc[mt][nt]);
            }
    }

    // epilogue: lane -> m = mbase+mt*16+l15 ; n0 = nt*16+lq*4
#pragma unroll
    for (int mt = 0; mt < 2; ++mt) {
        int m = mbase + mt * 16 + l15;
        if (m >= nrows) continue;
        float d = dis[m];
        float sn = d * d;
#pragma unroll
        for (int nt = 0; nt < 8; ++nt) {
            int n0 = nt * 16 + lq * 4;
            float4 bv = *(const float4*)&bias[n0];
            f32x4 a = acc[mt][nt];
            float4 hp = {bv.x + sn * a[0], bv.y + sn * a[1],
                         bv.z + sn * a[2], bv.w + sn * a[3]};
            *(float4*)&hpre[m * 128 + n0] = hp;
            int pk = __builtin_amdgcn_cvt_pk_fp8_f32(a[0] * 16.f, a[1] * 16.f, 0, false);
            pk = __builtin_amdgcn_cvt_pk_fp8_f32(a[2] * 16.f, a[3] * 16.f, pk, true);
            mb8[(m * 128 + n0) >> 2] = (unsigned int)pk;
        }
    }
}

// ---------------- gather: h = relu(hpre + sum_e nrm*fp8(m[src])) -> hi/lo bf16 split ----------------
// Single pass; eps order per node is [src<25K | src>=25K], giving statistical phase
// alignment of the random mb8 working set (~3.2MB at a time) across concurrent blocks.
__device__ inline void accp(float4& a, float n, unsigned int m) {
    f32x2 lo = __builtin_amdgcn_cvt_pk_f32_fp8(m, false);
    f32x2 hi = __builtin_amdgcn_cvt_pk_f32_fp8(m, true);
    a.x = fmaf(n, lo[0], a.x);
    a.y = fmaf(n, lo[1], a.y);
    a.z = fmaf(n, hi[0], a.z);
    a.w = fmaf(n, hi[1], a.w);
}

__global__ __launch_bounds__(256) void gather_kernel(const int* __restrict__ rowptr,
                                                     const unsigned int* __restrict__ eps,
                                                     const float* __restrict__ hpre,
                                                     const unsigned int* __restrict__ mb8,
                                                     unsigned short* __restrict__ hhi,
                                                     unsigned short* __restrict__ hlo) {
    int nid = blockIdx.x * 8 + (threadIdx.x >> 5);
    if (nid >= N_NODES) return;
    int fq = threadIdx.x & 31;              // uint index within 128B fp8 row
    int f = fq * 4;

    float4 a = *(const float4*)&hpre[nid * HDIM + f];

    int e = rowptr[nid];
    int e1 = rowptr[nid + 1];
    for (; e + 3 < e1; e += 4) {
        unsigned int p0 = eps[e], p1 = eps[e + 1], p2 = eps[e + 2], p3 = eps[e + 3];
        unsigned int m0 = mb8[(p0 & 0xFFFFu) * 32 + fq];
        unsigned int m1 = mb8[(p1 & 0xFFFFu) * 32 + fq];
        unsigned int m2 = mb8[(p2 & 0xFFFFu) * 32 + fq];
        unsigned int m3 = mb8[(p3 & 0xFFFFu) * 32 + fq];
        accp(a, __uint_as_float(p0 & 0xFFFF0000u), m0);
        accp(a, __uint_as_float(p1 & 0xFFFF0000u), m1);
        accp(a, __uint_as_float(p2 & 0xFFFF0000u), m2);
        accp(a, __uint_as_float(p3 & 0xFFFF0000u), m3);
    }
    for (; e < e1; ++e) {
        unsigned int p0 = eps[e];
        unsigned int m0 = mb8[(p0 & 0xFFFFu) * 32 + fq];
        accp(a, __uint_as_float(p0 & 0xFFFF0000u), m0);
    }
    // relu + hi/lo split
    float xs[4] = {fmaxf(a.x, 0.f), fmaxf(a.y, 0.f), fmaxf(a.z, 0.f), fmaxf(a.w, 0.f)};
    unsigned int hb[4], lb[4];
#pragma unroll
    for (int j = 0; j < 4; ++j) {
        hb[j] = f2bf(xs[j]);
        lb[j] = f2bf(xs[j] - bf2f(hb[j]));
    }
    ushort4 vh = {(unsigned short)hb[0], (unsigned short)hb[1],
                  (unsigned short)hb[2], (unsigned short)hb[3]};
    ushort4 vl = {(unsigned short)lb[0], (unsigned short)lb[1],
                  (unsigned short)lb[2], (unsigned short)lb[3]};
    *(ushort4*)&hhi[nid * HDIM + f] = vh;
    *(ushort4*)&hlo[nid * HDIM + f] = vl;
}

// ---- pool: g[batch[i]] += h[i]; 64 nodes/block, u32 packed loads, 2 features/thread ----
__global__ __launch_bounds__(256) void pool_kernel(const unsigned int* __restrict__ hh32,
                                                   const unsigned int* __restrict__ hl32,
                                                   const int* __restrict__ batch,
                                                   float* __restrict__ g) {
    int fp = threadIdx.x & 63;          // feature pair (2*fp, 2*fp+1)
    int nl = threadIdx.x >> 6;          // node lane 0..3
    int i0 = blockIdx.x * 64 + nl;
    int iend = min(blockIdx.x * 64 + 64, N_NODES);
    float ax = 0.f, ay = 0.f;
    int cur = -1;
    for (int i = i0; i < iend; i += 4) {
        int bb = batch[i];
        if (bb != cur) {
            if (cur >= 0) {
                unsafeAtomicAdd(&g[cur * HDIM + fp * 2], ax);
                unsafeAtomicAdd(&g[cur * HDIM + fp * 2 + 1], ay);
            }
            ax = 0.f; ay = 0.f; cur = bb;
        }
        unsigned int vh = hh32[i * 64 + fp];
        unsigned int vl = hl32[i * 64 + fp];
        ax += bf2f(vh & 0xFFFFu) + bf2f(vl & 0xFFFFu);
        ay += bf2f(vh >> 16) + bf2f(vl >> 16);
    }
    if (cur >= 0) {
        unsafeAtomicAdd(&g[cur * HDIM + fp * 2], ax);
        unsafeAtomicAdd(&g[cur * HDIM + fp * 2 + 1], ay);
    }
}

// ---------------- MLP head + log_softmax: one block per graph ----------------
__global__ __launch_bounds__(128) void mlp_kernel(const float* __restrict__ g,
                                                  const float* __restrict__ lw1,
                                                  const float* __restrict__ lb1,
                                                  const float* __restrict__ lw2,
                                                  const float* __restrict__ lb2,
                                                  float* __restrict__ out) {
    __shared__ float sg[128];
    __shared__ float sh[128];
    __shared__ float sl[NCLS];
    __shared__ float s_lse;
    int b = blockIdx.x;
    int t = threadIdx.x;
    sg[t] = g[b * HDIM + t];
    __syncthreads();
    float acc = lb1[t];
    for (int k = 0; k < 128; ++k) acc = fmaf(sg[k], lw1[k * 128 + t], acc);
    sh[t] = fmaxf(acc, 0.f);
    __syncthreads();
    if (t < NCLS) {
        float a2 = lb2[t];
        for (int j = 0; j < 128; ++j) a2 = fmaf(sh[j], lw2[j * NCLS + t], a2);
        sl[t] = a2;
    }
    __syncthreads();
    if (t == 0) {
        float mx = sl[0];
        for (int c = 1; c < NCLS; ++c) mx = fmaxf(mx, sl[c]);
        float se = 0.f;
        for (int c = 0; c < NCLS; ++c) se += expf(sl[c] - mx);
        s_lse = mx + logf(se);
    }
    __syncthreads();
    if (t < NCLS) out[b * NCLS + t] = sl[t] - s_lse;
}

extern "C" void kernel_launch(void* const* d_in, const int* in_sizes, int n_in,
                              void* d_out, int out_size, void* d_ws, size_t ws_size,
                              hipStream_t stream) {
    const float* x     = (const float*)d_in[0];
    const int*   ei    = (const int*)d_in[1];     // [2, E] flat
    const float* ew    = (const float*)d_in[2];
    const int*   batch = (const int*)d_in[3];
    const float* W[5]  = {(const float*)d_in[4],  (const float*)d_in[6],
                          (const float*)d_in[8],  (const float*)d_in[10],
                          (const float*)d_in[12]};
    const float* B[5]  = {(const float*)d_in[5],  (const float*)d_in[7],
                          (const float*)d_in[9],  (const float*)d_in[11],
                          (const float*)d_in[13]};
    const float* lw1   = (const float*)d_in[14];
    const float* lb1   = (const float*)d_in[15];
    const float* lw2   = (const float*)d_in[16];
    const float* lb2   = (const float*)d_in[17];
    float* out = (float*)d_out;

    const int* row = ei;
    const int* col = ei + N_EDGES;

    // workspace layout (4-byte words), ~85 MB total
    float* ws     = (float*)d_ws;
    float* sumsq  = ws;                                        // 16
    float* dis    = ws + 16;                                   // 50048
    int*   rowptr = (int*)(dis + 50048);                       // 50064
    int*   Hg     = rowptr + 50064;                            // 152896 (391*391 padded)
    int*   Bt     = Hg + 152896;                               // 400
    int*   Bb     = Bt + 400;                                  // 400 (needs 392)
    uint2* R      = (uint2*)(Bb + 400);                        // E uint2 (3.2M words)
    uint2* S      = R + N_EDGES;                               // E uint2 (3.2M words)
    float* g      = (float*)(S + N_EDGES);                     // 8192
    unsigned short* wthi = (unsigned short*)(g + NGRAPH * HDIM); // 5*16384 us
    unsigned short* wtlo = wthi + 5 * 128 * 128;                 // 5*16384 us
    float* hpre   = (float*)(wtlo + 5 * 128 * 128);            // N*128 f32
    unsigned int* mb8 = (unsigned int*)(hpre + N_NODES * HDIM); // N*32 u32 (fp8 m)
    unsigned short* hhi = (unsigned short*)(mb8 + N_NODES * 32); // N*128 us
    unsigned short* hlo = hhi + N_NODES * HDIM;                // N*128 us
    unsigned int* eps = (unsigned int*)R;                      // alias: R dead after nstat

    const int EB = N_EDGES / 256;                              // 6250

    wconv_kernel<<<dim3(8, 5), 256, 0, stream>>>(W[0], W[1], W[2], W[3], W[4],
                                                 wthi, wtlo, sumsq, g);
    hist_kernel<<<HB, 256, 0, stream>>>(col, ew, sumsq, Hg);
    btot_kernel<<<NBKT, 256, 0, stream>>>(Hg, Bt);
    bscan_kernel<<<1, 512, 0, stream>>>(Bt, Bb);
    hscan_kernel<<<NBKT, 512, 0, stream>>>(Bb, Hg);
    scat_kernel<<<HB, 256, 0, stream>>>(col, row, ew, Hg, R);
    nstat_kernel<<<NBKT, 256, 0, stream>>>(R, Bb, sumsq, dis, rowptr, S);
    fill2_kernel<<<EB, 256, 0, stream>>>(S, sumsq, dis, eps);

    const int GEMM_B = (N_NODES + 127) / 128;                  // 391
    const int GATH_B = (N_NODES + 7) / 8;                      // 6250
    const int POOL_B = (N_NODES + 63) / 64;                    // 782

    // layer 1: A = x (fp32, split in-kernel)
    gemm_mfma<1><<<GEMM_B, 256, 0, stream>>>(x, hhi, hlo, wthi, wtlo,
                                             dis, B[0], hpre, mb8, N_NODES);
    gather_kernel<<<GATH_B, 256, 0, stream>>>(rowptr, eps, hpre, mb8, hhi, hlo);
    // layers 2..5: A = h (hi/lo bf16 split, pre-relu'd by gather)
    for (int l = 1; l < 5; ++l) {
        gemm_mfma<0><<<GEMM_B, 256, 0, stream>>>(x, hhi, hlo,
                                                 wthi + l * 128 * 128, wtlo + l * 128 * 128,
                                                 dis, B[l], hpre, mb8, N_NODES);
        gather_kernel<<<GATH_B, 256, 0, stream>>>(rowptr, eps, hpre, mb8, hhi, hlo);
    }

    // pool + head
    pool_kernel<<<POOL_B, 256, 0, stream>>>((const unsigned int*)hhi, (const unsigned int*)hlo,
                                            batch, g);
    mlp_kernel<<<NGRAPH, 128, 0, stream>>>(g, lw1, lb1, lw2, lb2, out);
}

// Round 12
// 385.068 us; speedup vs baseline: 1.5829x; 1.1089x over previous
//
#include <hip/hip_runtime.h>
#include <hip/hip_bf16.h>

#define N_NODES 50000
#define N_EDGES 1600000
#define HDIM    128
#define NCLS    10
#define NGRAPH  64
#define NBKT    391        // buckets of 128 nodes: col>>7
#define HB      391        // histogram/scatter blocks: 4096 edges each

typedef __attribute__((ext_vector_type(8))) short bf16x8;
typedef __attribute__((ext_vector_type(4))) float f32x4;
typedef __attribute__((ext_vector_type(2))) float f32x2;

// float -> bf16 bits (round-to-nearest-even), values are finite
__device__ inline unsigned int f2bf(float x) {
    unsigned int u = __float_as_uint(x);
    return (u + 0x7FFFu + ((u >> 16) & 1u)) >> 16;
}
__device__ inline float bf2f(unsigned int h) { return __uint_as_float(h << 16); }

__device__ inline f32x4 mfma16(bf16x8 a, bf16x8 b, f32x4 c) {
    return __builtin_amdgcn_mfma_f32_16x16x32_bf16(a, b, c, 0, 0, 0);
}

// ---------------- hist: per-block bucket histogram (col>>7) + sumsq ----------------
__global__ __launch_bounds__(256) void hist_kernel(const int* __restrict__ col,
                                                   const float* __restrict__ ew,
                                                   float* __restrict__ sumsq,
                                                   int* __restrict__ Hg) {
    __shared__ int hist[NBKT];
    __shared__ float part[4];
    int b = blockIdx.x, t = threadIdx.x;
    for (int i = t; i < NBKT; i += 256) hist[i] = 0;
    __syncthreads();
    int base = b * 4096;
    float ss = 0.f;
#pragma unroll
    for (int j = 0; j < 16; ++j) {
        int idx = base + j * 256 + t;
        if (idx < N_EDGES) {
            atomicAdd(&hist[col[idx] >> 7], 1);
            float w = ew[idx];
            ss += w * w;
        }
    }
#pragma unroll
    for (int off = 32; off > 0; off >>= 1) ss += __shfl_down(ss, off);
    if ((t & 63) == 0) part[t >> 6] = ss;
    __syncthreads();
    if (t == 0) unsafeAtomicAdd(sumsq, part[0] + part[1] + part[2] + part[3]);
    for (int i = t; i < NBKT; i += 256) Hg[i * HB + b] = hist[i];
}

// ---------------- btot: per-bucket total over blocks ----------------
__global__ __launch_bounds__(256) void btot_kernel(const int* __restrict__ Hg,
                                                   int* __restrict__ Bt) {
    __shared__ int s[256];
    int i = blockIdx.x, t = threadIdx.x;
    int v = (t < HB) ? Hg[i * HB + t] : 0;
    if (t + 256 < HB) v += Hg[i * HB + t + 256];
    s[t] = v;
    __syncthreads();
#pragma unroll
    for (int off = 128; off > 0; off >>= 1) {
        if (t < off) s[t] += s[t + off];
        __syncthreads();
    }
    if (t == 0) Bt[i] = s[0];
}

// ---------------- bscan: exclusive scan of bucket totals -> bucket bases ----------------
__global__ __launch_bounds__(512) void bscan_kernel(const int* __restrict__ Bt,
                                                    int* __restrict__ Bb) {
    __shared__ int s[512];
    int t = threadIdx.x;
    int v = (t < NBKT) ? Bt[t] : 0;
    s[t] = v;
    __syncthreads();
#pragma unroll
    for (int off = 1; off < 512; off <<= 1) {
        int add = (t >= off) ? s[t - off] : 0;
        __syncthreads();
        s[t] += add;
        __syncthreads();
    }
    if (t < NBKT) Bb[t] = s[t] - v;
    if (t == 0) Bb[NBKT] = N_EDGES;
}

// ---------------- hscan: per-bucket exclusive scan over blocks + bucket base ----------------
__global__ __launch_bounds__(512) void hscan_kernel(const int* __restrict__ Bb,
                                                    int* __restrict__ Hg) {
    __shared__ int s[512];
    int i = blockIdx.x, t = threadIdx.x;
    int v = (t < HB) ? Hg[i * HB + t] : 0;
    s[t] = v;
    __syncthreads();
#pragma unroll
    for (int off = 1; off < 512; off <<= 1) {
        int add = (t >= off) ? s[t - off] : 0;
        __syncthreads();
        s[t] += add;
        __syncthreads();
    }
    if (t < HB) Hg[i * HB + t] = Bb[i] + s[t] - v;
}

// ---------------- scat: bucket-grouped records (col16|row16, ew) via LDS cursors ----------------
__global__ __launch_bounds__(256) void scat_kernel(const int* __restrict__ col,
                                                   const int* __restrict__ row,
                                                   const float* __restrict__ ew,
                                                   const int* __restrict__ Hg,
                                                   uint2* __restrict__ R) {
    __shared__ int cur[NBKT];
    int b = blockIdx.x, t = threadIdx.x;
    for (int i = t; i < NBKT; i += 256) cur[i] = Hg[i * HB + b];
    __syncthreads();
    int base = b * 4096;
#pragma unroll
    for (int j = 0; j < 16; ++j) {
        int idx = base + j * 256 + t;
        if (idx < N_EDGES) {
            int c = col[idx];
            int r = row[idx];
            float w = ew[idx];
            int slot = atomicAdd(&cur[c >> 7], 1);
            R[slot] = make_uint2(((unsigned int)c << 16) | (unsigned int)r,
                                 __float_as_uint(w));
        }
    }
}

// ---- nstat: per-bucket node stats + rowptr + dis + DIRECT eps write ----
// eps norm = (w*rn)*dis[c]/16 — dis[src] is folded into the fp8 message by gemm,
// so no cross-bucket dis dependency and fill2 is eliminated.
__global__ __launch_bounds__(256) void nstat_kernel(const uint2* __restrict__ R,
                                                    const int* __restrict__ Bb,
                                                    const float* __restrict__ sumsq,
                                                    float* __restrict__ dis,
                                                    int* __restrict__ rowptr,
                                                    unsigned int* __restrict__ eps) {
    __shared__ int cnt[128];
    __shared__ float degf[128];
    __shared__ int scn[128];
    __shared__ int loc[128];
    __shared__ float sdis[128];
    int bkt = blockIdx.x, t = threadIdx.x;
    int bstart = Bb[bkt], bend = Bb[bkt + 1];
    int node0 = bkt << 7;
    if (t < 128) { cnt[t] = 0; degf[t] = 0.f; }
    __syncthreads();
    for (int i = bstart + t; i < bend; i += 256) {
        uint2 r = R[i];
        int cl = (int)(r.x >> 16) - node0;
        atomicAdd(&cnt[cl], 1);
        atomicAdd(&degf[cl], __uint_as_float(r.y));
    }
    __syncthreads();
    if (t < 128) scn[t] = cnt[t];
    __syncthreads();
#pragma unroll
    for (int off = 1; off < 128; off <<= 1) {
        int add = (t < 128 && t >= off) ? scn[t - off] : 0;
        __syncthreads();
        if (t < 128) scn[t] += add;
        __syncthreads();
    }
    if (t < 128) loc[t] = scn[t] - cnt[t];          // exclusive cursor
    int nNodes = min(128, N_NODES - node0);
    float rn = 1.f / fmaxf(sqrtf(sumsq[0]), 1e-12f);
    if (t < nNodes) {
        rowptr[node0 + t] = bstart + scn[t] - cnt[t];
        float d = rsqrtf(1.f + degf[t] * rn);
        dis[node0 + t] = d;
        sdis[t] = d;
    }
    if (bkt == NBKT - 1 && t == 0) rowptr[N_NODES] = bend;
    __syncthreads();
    for (int i = bstart + t; i < bend; i += 256) {
        uint2 r = R[i];
        int cl = (int)(r.x >> 16) - node0;
        int slot = atomicAdd(&loc[cl], 1);
        float nr = __uint_as_float(r.y) * rn * sdis[cl] * 0.0625f;
        eps[bstart + slot] = (f2bf(nr) << 16) | (r.x & 0xFFFFu);
    }
}

// ---------------- W -> Wt (transposed, hi/lo bf16 split) + init (sumsq=0, g=0) ----------------
__global__ __launch_bounds__(256) void wconv_kernel(const float* __restrict__ W0,
                                                    const float* __restrict__ W1,
                                                    const float* __restrict__ W2,
                                                    const float* __restrict__ W3,
                                                    const float* __restrict__ W4,
                                                    unsigned short* __restrict__ wthi,
                                                    unsigned short* __restrict__ wtlo,
                                                    float* __restrict__ sumsq,
                                                    float* __restrict__ g) {
    int fid = (blockIdx.y * 8 + blockIdx.x) * 256 + threadIdx.x;   // 0..10239
    if (fid < NGRAPH * HDIM) g[fid] = 0.f;
    if (fid == NGRAPH * HDIM) sumsq[0] = 0.f;

    const float* Ws[5] = {W0, W1, W2, W3, W4};
    const float* W = Ws[blockIdx.y];
    unsigned short* hi = wthi + blockIdx.y * 128 * 128;
    unsigned short* lo = wtlo + blockIdx.y * 128 * 128;
    int t = blockIdx.x * 256 + threadIdx.x;   // 0..2047
    int n  = t & 127;
    int kb = t >> 7;                          // 0..15
    unsigned int hh[8], ll[8];
#pragma unroll
    for (int j = 0; j < 8; ++j) {
        float w = W[(kb * 8 + j) * 128 + n];   // W[k][n] -> Wt[n][k]
        unsigned int hb = f2bf(w);
        float r = w - bf2f(hb);
        hh[j] = hb; ll[j] = f2bf(r);
    }
    uint4 vh, vl;
    vh.x = hh[0] | (hh[1] << 16); vh.y = hh[2] | (hh[3] << 16);
    vh.z = hh[4] | (hh[5] << 16); vh.w = hh[6] | (hh[7] << 16);
    vl.x = ll[0] | (ll[1] << 16); vl.y = ll[2] | (ll[3] << 16);
    vl.z = ll[4] | (ll[5] << 16); vl.w = ll[6] | (ll[7] << 16);
    *(uint4*)&hi[n * 128 + kb * 8] = vh;
    *(uint4*)&lo[n * 128 + kb * 8] = vl;
}

// ---------------- MFMA GEMM: M = A @ W, hpre = bias + dis^2*M, mb8 = fp8(16*dis*M) ----------------
template <int FP32A>
__global__ __launch_bounds__(256) void gemm_mfma(const float* __restrict__ Af,
                                                 const unsigned short* __restrict__ Ahi,
                                                 const unsigned short* __restrict__ Alo,
                                                 const unsigned short* __restrict__ Wthi,
                                                 const unsigned short* __restrict__ Wtlo,
                                                 const float* __restrict__ dis,
                                                 const float* __restrict__ bias,
                                                 float* __restrict__ hpre,
                                                 unsigned int* __restrict__ mb8,
                                                 int nrows) {
    const int lane = threadIdx.x & 63;
    const int wave = threadIdx.x >> 6;
    const int l15  = lane & 15;
    const int lq   = lane >> 4;              // 0..3
    const int mbase = blockIdx.x * 128 + wave * 32;

    f32x4 acc[2][8];
#pragma unroll
    for (int i = 0; i < 2; ++i)
#pragma unroll
        for (int j = 0; j < 8; ++j) acc[i][j] = (f32x4){0.f, 0.f, 0.f, 0.f};

#pragma unroll
    for (int ks = 0; ks < 4; ++ks) {
        const int kof = ks * 32 + lq * 8;
        bf16x8 wh[8], wl[8];
#pragma unroll
        for (int nt = 0; nt < 8; ++nt) {
            int n = nt * 16 + l15;
            wh[nt] = *(const bf16x8*)&Wthi[n * 128 + kof];
            wl[nt] = *(const bf16x8*)&Wtlo[n * 128 + kof];
        }
        bf16x8 ah[2], al[2];
#pragma unroll
        for (int mt = 0; mt < 2; ++mt) {
            int m = mbase + mt * 16 + l15;
            if (m < nrows) {
                if (FP32A) {
                    const float* ap = &Af[m * 128 + kof];
                    float4 v0 = *(const float4*)&ap[0];
                    float4 v1 = *(const float4*)&ap[4];
                    float xs[8] = {v0.x, v0.y, v0.z, v0.w, v1.x, v1.y, v1.z, v1.w};
                    short hh[8], ll[8];
#pragma unroll
                    for (int j = 0; j < 8; ++j) {
                        unsigned int hb = f2bf(xs[j]);
                        float r = xs[j] - bf2f(hb);
                        hh[j] = (short)hb;
                        ll[j] = (short)f2bf(r);
                    }
                    ah[mt] = (bf16x8){hh[0], hh[1], hh[2], hh[3], hh[4], hh[5], hh[6], hh[7]};
                    al[mt] = (bf16x8){ll[0], ll[1], ll[2], ll[3], ll[4], ll[5], ll[6], ll[7]};
                } else {
                    ah[mt] = *(const bf16x8*)&Ahi[m * 128 + kof];
                    al[mt] = *(const bf16x8*)&Alo[m * 128 + kof];
                }
            } else {
                ah[mt] = (bf16x8){0, 0, 0, 0, 0, 0, 0, 0};
                al[mt] = (bf16x8){0, 0, 0, 0, 0, 0, 0, 0};
            }
        }
#pragma unroll
        for (int mt = 0; mt < 2; ++mt)
#pragma unroll
            for (int nt = 0; nt < 8; ++nt) {
                acc[mt][nt] = mfma16(wh[nt], ah[mt], acc[mt][nt]);
                acc[mt][nt] = mfma16(wl[nt], ah[mt], acc[mt][nt]);
                acc[mt][nt] = mfma16(wh[nt], al[mt], acc[mt][nt]);
            }
    }

    // epilogue: lane -> m = mbase+mt*16+l15 ; n0 = nt*16+lq*4
#pragma unroll
    for (int mt = 0; mt < 2; ++mt) {
        int m = mbase + mt * 16 + l15;
        if (m >= nrows) continue;
        float d = dis[m];
        float sn = d * d;
        float ds16 = d * 16.f;
#pragma unroll
        for (int nt = 0; nt < 8; ++nt) {
            int n0 = nt * 16 + lq * 4;
            float4 bv = *(const float4*)&bias[n0];
            f32x4 a = acc[mt][nt];
            float4 hp = {bv.x + sn * a[0], bv.y + sn * a[1],
                         bv.z + sn * a[2], bv.w + sn * a[3]};
            *(float4*)&hpre[m * 128 + n0] = hp;
            int pk = __builtin_amdgcn_cvt_pk_fp8_f32(a[0] * ds16, a[1] * ds16, 0, false);
            pk = __builtin_amdgcn_cvt_pk_fp8_f32(a[2] * ds16, a[3] * ds16, pk, true);
            mb8[(m * 128 + n0) >> 2] = (unsigned int)pk;
        }
    }
}

// ---------------- gather: h = relu(hpre + sum_e nrm*fp8msg) -> hi/lo bf16 split ----------------
// 8-edge unroll: 8 independent random mb8 loads in flight per lane (latency hiding).
__device__ inline void accp(float4& a, float n, unsigned int m) {
    f32x2 lo = __builtin_amdgcn_cvt_pk_f32_fp8(m, false);
    f32x2 hi = __builtin_amdgcn_cvt_pk_f32_fp8(m, true);
    a.x = fmaf(n, lo[0], a.x);
    a.y = fmaf(n, lo[1], a.y);
    a.z = fmaf(n, hi[0], a.z);
    a.w = fmaf(n, hi[1], a.w);
}

__global__ __launch_bounds__(256) void gather_kernel(const int* __restrict__ rowptr,
                                                     const unsigned int* __restrict__ eps,
                                                     const float* __restrict__ hpre,
                                                     const unsigned int* __restrict__ mb8,
                                                     unsigned short* __restrict__ hhi,
                                                     unsigned short* __restrict__ hlo) {
    int nid = blockIdx.x * 8 + (threadIdx.x >> 5);
    if (nid >= N_NODES) return;
    int fq = threadIdx.x & 31;              // uint index within 128B fp8 row
    int f = fq * 4;

    float4 a = *(const float4*)&hpre[nid * HDIM + f];

    int e = rowptr[nid];
    int e1 = rowptr[nid + 1];
    for (; e + 7 < e1; e += 8) {
        unsigned int p0 = eps[e],     p1 = eps[e + 1], p2 = eps[e + 2], p3 = eps[e + 3];
        unsigned int p4 = eps[e + 4], p5 = eps[e + 5], p6 = eps[e + 6], p7 = eps[e + 7];
        unsigned int m0 = mb8[(p0 & 0xFFFFu) * 32 + fq];
        unsigned int m1 = mb8[(p1 & 0xFFFFu) * 32 + fq];
        unsigned int m2 = mb8[(p2 & 0xFFFFu) * 32 + fq];
        unsigned int m3 = mb8[(p3 & 0xFFFFu) * 32 + fq];
        unsigned int m4 = mb8[(p4 & 0xFFFFu) * 32 + fq];
        unsigned int m5 = mb8[(p5 & 0xFFFFu) * 32 + fq];
        unsigned int m6 = mb8[(p6 & 0xFFFFu) * 32 + fq];
        unsigned int m7 = mb8[(p7 & 0xFFFFu) * 32 + fq];
        accp(a, __uint_as_float(p0 & 0xFFFF0000u), m0);
        accp(a, __uint_as_float(p1 & 0xFFFF0000u), m1);
        accp(a, __uint_as_float(p2 & 0xFFFF0000u), m2);
        accp(a, __uint_as_float(p3 & 0xFFFF0000u), m3);
        accp(a, __uint_as_float(p4 & 0xFFFF0000u), m4);
        accp(a, __uint_as_float(p5 & 0xFFFF0000u), m5);
        accp(a, __uint_as_float(p6 & 0xFFFF0000u), m6);
        accp(a, __uint_as_float(p7 & 0xFFFF0000u), m7);
    }
    for (; e + 3 < e1; e += 4) {
        unsigned int p0 = eps[e], p1 = eps[e + 1], p2 = eps[e + 2], p3 = eps[e + 3];
        unsigned int m0 = mb8[(p0 & 0xFFFFu) * 32 + fq];
        unsigned int m1 = mb8[(p1 & 0xFFFFu) * 32 + fq];
        unsigned int m2 = mb8[(p2 & 0xFFFFu) * 32 + fq];
        unsigned int m3 = mb8[(p3 & 0xFFFFu) * 32 + fq];
        accp(a, __uint_as_float(p0 & 0xFFFF0000u), m0);
        accp(a, __uint_as_float(p1 & 0xFFFF0000u), m1);
        accp(a, __uint_as_float(p2 & 0xFFFF0000u), m2);
        accp(a, __uint_as_float(p3 & 0xFFFF0000u), m3);
    }
    for (; e < e1; ++e) {
        unsigned int p0 = eps[e];
        unsigned int m0 = mb8[(p0 & 0xFFFFu) * 32 + fq];
        accp(a, __uint_as_float(p0 & 0xFFFF0000u), m0);
    }
    // relu + hi/lo split
    float xs[4] = {fmaxf(a.x, 0.f), fmaxf(a.y, 0.f), fmaxf(a.z, 0.f), fmaxf(a.w, 0.f)};
    unsigned int hb[4], lb[4];
#pragma unroll
    for (int j = 0; j < 4; ++j) {
        hb[j] = f2bf(xs[j]);
        lb[j] = f2bf(xs[j] - bf2f(hb[j]));
    }
    ushort4 vh = {(unsigned short)hb[0], (unsigned short)hb[1],
                  (unsigned short)hb[2], (unsigned short)hb[3]};
    ushort4 vl = {(unsigned short)lb[0], (unsigned short)lb[1],
                  (unsigned short)lb[2], (unsigned short)lb[3]};
    *(ushort4*)&hhi[nid * HDIM + f] = vh;
    *(ushort4*)&hlo[nid * HDIM + f] = vl;
}

// ---- pool: g[batch[i]] += h[i]; 64 nodes/block, u32 packed loads, 2 features/thread ----
__global__ __launch_bounds__(256) void pool_kernel(const unsigned int* __restrict__ hh32,
                                                   const unsigned int* __restrict__ hl32,
                                                   const int* __restrict__ batch,
                                                   float* __restrict__ g) {
    int fp = threadIdx.x & 63;          // feature pair (2*fp, 2*fp+1)
    int nl = threadIdx.x >> 6;          // node lane 0..3
    int i0 = blockIdx.x * 64 + nl;
    int iend = min(blockIdx.x * 64 + 64, N_NODES);
    float ax = 0.f, ay = 0.f;
    int cur = -1;
    for (int i = i0; i < iend; i += 4) {
        int bb = batch[i];
        if (bb != cur) {
            if (cur >= 0) {
                unsafeAtomicAdd(&g[cur * HDIM + fp * 2], ax);
                unsafeAtomicAdd(&g[cur * HDIM + fp * 2 + 1], ay);
            }
            ax = 0.f; ay = 0.f; cur = bb;
        }
        unsigned int vh = hh32[i * 64 + fp];
        unsigned int vl = hl32[i * 64 + fp];
        ax += bf2f(vh & 0xFFFFu) + bf2f(vl & 0xFFFFu);
        ay += bf2f(vh >> 16) + bf2f(vl >> 16);
    }
    if (cur >= 0) {
        unsafeAtomicAdd(&g[cur * HDIM + fp * 2], ax);
        unsafeAtomicAdd(&g[cur * HDIM + fp * 2 + 1], ay);
    }
}

// ---------------- MLP head + log_softmax: one block per graph ----------------
__global__ __launch_bounds__(128) void mlp_kernel(const float* __restrict__ g,
                                                  const float* __restrict__ lw1,
                                                  const float* __restrict__ lb1,
                                                  const float* __restrict__ lw2,
                                                  const float* __restrict__ lb2,
                                                  float* __restrict__ out) {
    __shared__ float sg[128];
    __shared__ float sh[128];
    __shared__ float sl[NCLS];
    __shared__ float s_lse;
    int b = blockIdx.x;
    int t = threadIdx.x;
    sg[t] = g[b * HDIM + t];
    __syncthreads();
    float acc = lb1[t];
    for (int k = 0; k < 128; ++k) acc = fmaf(sg[k], lw1[k * 128 + t], acc);
    sh[t] = fmaxf(acc, 0.f);
    __syncthreads();
    if (t < NCLS) {
        float a2 = lb2[t];
        for (int j = 0; j < 128; ++j) a2 = fmaf(sh[j], lw2[j * NCLS + t], a2);
        sl[t] = a2;
    }
    __syncthreads();
    if (t == 0) {
        float mx = sl[0];
        for (int c = 1; c < NCLS; ++c) mx = fmaxf(mx, sl[c]);
        float se = 0.f;
        for (int c = 0; c < NCLS; ++c) se += expf(sl[c] - mx);
        s_lse = mx + logf(se);
    }
    __syncthreads();
    if (t < NCLS) out[b * NCLS + t] = sl[t] - s_lse;
}

extern "C" void kernel_launch(void* const* d_in, const int* in_sizes, int n_in,
                              void* d_out, int out_size, void* d_ws, size_t ws_size,
                              hipStream_t stream) {
    const float* x     = (const float*)d_in[0];
    const int*   ei    = (const int*)d_in[1];     // [2, E] flat
    const float* ew    = (const float*)d_in[2];
    const int*   batch = (const int*)d_in[3];
    const float* W[5]  = {(const float*)d_in[4],  (const float*)d_in[6],
                          (const float*)d_in[8],  (const float*)d_in[10],
                          (const float*)d_in[12]};
    const float* B[5]  = {(const float*)d_in[5],  (const float*)d_in[7],
                          (const float*)d_in[9],  (const float*)d_in[11],
                          (const float*)d_in[13]};
    const float* lw1   = (const float*)d_in[14];
    const float* lb1   = (const float*)d_in[15];
    const float* lw2   = (const float*)d_in[16];
    const float* lb2   = (const float*)d_in[17];
    float* out = (float*)d_out;

    const int* row = ei;
    const int* col = ei + N_EDGES;

    // workspace layout (4-byte words), ~95 MB total
    float* ws     = (float*)d_ws;
    float* sumsq  = ws;                                        // 16
    float* dis    = ws + 16;                                   // 50048
    int*   rowptr = (int*)(dis + 50048);                       // 50064
    int*   Hg     = rowptr + 50064;                            // 152896 (391*391 padded)
    int*   Bt     = Hg + 152896;                               // 400
    int*   Bb     = Bt + 400;                                  // 400 (needs 392)
    uint2* R      = (uint2*)(Bb + 400);                        // E uint2 (3.2M words)
    unsigned int* eps = (unsigned int*)(R + N_EDGES);          // E u32
    float* g      = (float*)(eps + N_EDGES);                   // 8192
    unsigned short* wthi = (unsigned short*)(g + NGRAPH * HDIM); // 5*16384 us
    unsigned short* wtlo = wthi + 5 * 128 * 128;                 // 5*16384 us
    float* hpre   = (float*)(wtlo + 5 * 128 * 128);            // N*128 f32
    unsigned int* mb8 = (unsigned int*)(hpre + N_NODES * HDIM); // N*32 u32 (fp8 m)
    unsigned short* hhi = (unsigned short*)(mb8 + N_NODES * 32); // N*128 us
    unsigned short* hlo = hhi + N_NODES * HDIM;                // N*128 us

    wconv_kernel<<<dim3(8, 5), 256, 0, stream>>>(W[0], W[1], W[2], W[3], W[4],
                                                 wthi, wtlo, sumsq, g);
    hist_kernel<<<HB, 256, 0, stream>>>(col, ew, sumsq, Hg);
    btot_kernel<<<NBKT, 256, 0, stream>>>(Hg, Bt);
    bscan_kernel<<<1, 512, 0, stream>>>(Bt, Bb);
    hscan_kernel<<<NBKT, 512, 0, stream>>>(Bb, Hg);
    scat_kernel<<<HB, 256, 0, stream>>>(col, row, ew, Hg, R);
    nstat_kernel<<<NBKT, 256, 0, stream>>>(R, Bb, sumsq, dis, rowptr, eps);

    const int GEMM_B = (N_NODES + 127) / 128;                  // 391
    const int GATH_B = (N_NODES + 7) / 8;                      // 6250
    const int POOL_B = (N_NODES + 63) / 64;                    // 782

    // layer 1: A = x (fp32, split in-kernel)
    gemm_mfma<1><<<GEMM_B, 256, 0, stream>>>(x, hhi, hlo, wthi, wtlo,
                                             dis, B[0], hpre, mb8, N_NODES);
    gather_kernel<<<GATH_B, 256, 0, stream>>>(rowptr, eps, hpre, mb8, hhi, hlo);
    // layers 2..5: A = h (hi/lo bf16 split, pre-relu'd by gather)
    for (int l = 1; l < 5; ++l) {
        gemm_mfma<0><<<GEMM_B, 256, 0, stream>>>(x, hhi, hlo,
                                                 wthi + l * 128 * 128, wtlo + l * 128 * 128,
                                                 dis, B[l], hpre, mb8, N_NODES);
        gather_kernel<<<GATH_B, 256, 0, stream>>>(rowptr, eps, hpre, mb8, hhi, hlo);
    }

    // pool + head
    pool_kernel<<<POOL_B, 256, 0, stream>>>((const unsigned int*)hhi, (const unsigned int*)hlo,
                                            batch, g);
    mlp_kernel<<<NGRAPH, 128, 0, stream>>>(g, lw1, lb1, lw2, lb2, out);
}